// Round 2
// baseline (10924.184 us; speedup 1.0000x reference)
//
#include <hip/hip_runtime.h>
#include <math.h>

// Backprop_29188597744223 — 1024-step sequential MLP training scan.
//
//   k_gram : G = X·Xᵀ (lower triangle + diag tiles), grid-parallel
//   k_z10  : Z10 = X·W1_init, grid-parallel
//   k2_seq : ONE workgroup, 512 threads (8 waves). 4 barrier-fenced phases
//            per step (was 10):
//              A  : deferred W2/W3 rank-1 update (prev step) + z1 history + a1
//              BC : z2 via in-wave shfl split-tree, a2, z3 partials
//              DEF: per-wave redundant softmax/d3, o2 via in-wave tree,
//                   o1 partials, dot partials
//              GH : wave 0 reduces o1, updates b1/zo, runs all scalar norm
//                   recurrences (f64 n1), broadcasts 8 scalars via LDS
//            W2 layout: thread (w,lane) owns rows 4L..4L+3 × cols 32w..+31.
//            W3 layout: thread (w,lane) owns rows 32w..+31 × col lane.
//            Lazy scales s2/s3; biases pre-norm with rb folded at use; no
//            global stores in the step loop (o1/c flushed per 64-step block).
//   k_w1out: W1_final = s1_f·(W1_init + Xᵀ·diag(c)·O1), grid-parallel

#define LRC  0.01f
#define EPSV 1e-8f

typedef float f32x8 __attribute__((ext_vector_type(8)));

#define SMEM_FLOATS 36696
#define SMEM_BYTES  (SMEM_FLOATS * 4)

__device__ __forceinline__ float hsum8(f32x8 v) {
  return ((v.s0 + v.s1) + (v.s2 + v.s3)) + ((v.s4 + v.s5) + (v.s6 + v.s7));
}

__device__ __forceinline__ float wave_allred(float v) {
#pragma unroll
  for (int off = 32; off > 0; off >>= 1) v += __shfl_xor(v, off);
  return v;
}

// In-wave fence: order own-wave LDS write -> LDS read without s_barrier.
__device__ __forceinline__ void wave_fence() {
  __builtin_amdgcn_sched_barrier(0);
  asm volatile("s_waitcnt lgkmcnt(0)" ::: "memory");
  __builtin_amdgcn_sched_barrier(0);
}

// Reduce 32 lane-local partials v[i] (index i = col/row offset) over all 64
// lanes. Stage m keeps the half whose index-bit matches the lane bit, so the
// final mapping is natural: returns total for index (lane & 31).
__device__ __forceinline__ float xtree32(float v[32], const int lane) {
#pragma unroll
  for (int m = 1; m <= 16; m <<= 1) {
    const int n2 = 16 / m;
    const bool hi = (lane & m) != 0;
#pragma unroll
    for (int s = 0; s < n2; s++) {
      const float a = v[2 * s], b = v[2 * s + 1];
      const float send = hi ? a : b;
      const float keep = hi ? b : a;
      v[s] = keep + __shfl_xor(send, m);
    }
  }
  float r = v[0];
  r += __shfl_xor(r, 32);
  return r;
}

#define FMA16(c, a, b)                                                        \
  c[0][0] += a.x * b.x; c[0][1] += a.x * b.y; c[0][2] += a.x * b.z; c[0][3] += a.x * b.w; \
  c[1][0] += a.y * b.x; c[1][1] += a.y * b.y; c[1][2] += a.y * b.z; c[1][3] += a.y * b.w; \
  c[2][0] += a.z * b.x; c[2][1] += a.z * b.y; c[2][2] += a.z * b.z; c[2][3] += a.z * b.w; \
  c[3][0] += a.w * b.x; c[3][1] += a.w * b.y; c[3][2] += a.w * b.z; c[3][3] += a.w * b.w;

// ---------------------------------------------------------------- k_gram ----
__global__ __launch_bounds__(256) void k_gram(const float* __restrict__ X,
                                              float* __restrict__ G) {
  const int bi = blockIdx.y, bj = blockIdx.x;
  if (bj > bi) return;
  __shared__ float Xa[32][68];
  __shared__ float Xb[32][68];
  const int tid = threadIdx.x;
  const int tx = tid & 15, ty = tid >> 4;
  float c[4][4] = {};
  for (int k0 = 0; k0 < 1024; k0 += 32) {
    __syncthreads();
    {
      const int row = tid >> 2, kk = (tid & 3) * 8;
      const float* pa = X + (bi * 64 + row) * 1024 + k0 + kk;
      const float4 a0 = *(const float4*)pa;
      const float4 a1 = *(const float4*)(pa + 4);
      Xa[kk + 0][row] = a0.x; Xa[kk + 1][row] = a0.y;
      Xa[kk + 2][row] = a0.z; Xa[kk + 3][row] = a0.w;
      Xa[kk + 4][row] = a1.x; Xa[kk + 5][row] = a1.y;
      Xa[kk + 6][row] = a1.z; Xa[kk + 7][row] = a1.w;
      const float* pb = X + (bj * 64 + row) * 1024 + k0 + kk;
      const float4 b0 = *(const float4*)pb;
      const float4 b1 = *(const float4*)(pb + 4);
      Xb[kk + 0][row] = b0.x; Xb[kk + 1][row] = b0.y;
      Xb[kk + 2][row] = b0.z; Xb[kk + 3][row] = b0.w;
      Xb[kk + 4][row] = b1.x; Xb[kk + 5][row] = b1.y;
      Xb[kk + 6][row] = b1.z; Xb[kk + 7][row] = b1.w;
    }
    __syncthreads();
#pragma unroll
    for (int kk = 0; kk < 32; kk++) {
      const float4 a = *(const float4*)&Xa[kk][ty * 4];
      const float4 b = *(const float4*)&Xb[kk][tx * 4];
      FMA16(c, a, b)
    }
  }
#pragma unroll
  for (int ii = 0; ii < 4; ii++) {
    *(float4*)(G + (bi * 64 + ty * 4 + ii) * 1024 + bj * 64 + tx * 4) =
        make_float4(c[ii][0], c[ii][1], c[ii][2], c[ii][3]);
  }
}

// ----------------------------------------------------------------- k_z10 ----
__global__ __launch_bounds__(256) void k_z10(const float* __restrict__ X,
                                             const float* __restrict__ W1g,
                                             float* __restrict__ Z10) {
  const int bi = blockIdx.y, bj = blockIdx.x;
  __shared__ float At[32][68];
  __shared__ float Bt[32][68];
  const int tid = threadIdx.x;
  const int tx = tid & 15, ty = tid >> 4;
  float c[4][4] = {};
  for (int k0 = 0; k0 < 1024; k0 += 32) {
    __syncthreads();
    {
      const int row = tid >> 2, kk = (tid & 3) * 8;
      const float* pa = X + (bi * 64 + row) * 1024 + k0 + kk;
      const float4 a0 = *(const float4*)pa;
      const float4 a1 = *(const float4*)(pa + 4);
      At[kk + 0][row] = a0.x; At[kk + 1][row] = a0.y;
      At[kk + 2][row] = a0.z; At[kk + 3][row] = a0.w;
      At[kk + 4][row] = a1.x; At[kk + 5][row] = a1.y;
      At[kk + 6][row] = a1.z; At[kk + 7][row] = a1.w;
      const int kr = tid >> 3, j8 = (tid & 7) * 8;
      const float* pb = W1g + (k0 + kr) * 256 + bj * 64 + j8;
      *(float4*)&Bt[kr][j8]     = *(const float4*)pb;
      *(float4*)&Bt[kr][j8 + 4] = *(const float4*)(pb + 4);
    }
    __syncthreads();
#pragma unroll
    for (int kk = 0; kk < 32; kk++) {
      const float4 a = *(const float4*)&At[kk][ty * 4];
      const float4 b = *(const float4*)&Bt[kk][tx * 4];
      FMA16(c, a, b)
    }
  }
#pragma unroll
  for (int ii = 0; ii < 4; ii++) {
    *(float4*)(Z10 + (bi * 64 + ty * 4 + ii) * 256 + bj * 64 + tx * 4) =
        make_float4(c[ii][0], c[ii][1], c[ii][2], c[ii][3]);
  }
}

// --------------------------------------------------------------- k_w1out ----
__global__ __launch_bounds__(256) void k_w1out(
    const float* __restrict__ X, const float* __restrict__ o1g,
    const float* __restrict__ cg, const float* __restrict__ W1g,
    const float* __restrict__ sclg, float* __restrict__ outW1) {
  const int bi = blockIdx.y, bj = blockIdx.x;
  __shared__ float At[32][68];
  __shared__ float Bt[32][68];
  const int tid = threadIdx.x;
  const int tx = tid & 15, ty = tid >> 4;
  float c[4][4] = {};
  for (int k0 = 0; k0 < 1024; k0 += 32) {
    __syncthreads();
    {
      const int kr = tid >> 3, m8 = (tid & 7) * 8;
      const float* pa = X + (k0 + kr) * 1024 + bi * 64 + m8;
      *(float4*)&At[kr][m8]     = *(const float4*)pa;
      *(float4*)&At[kr][m8 + 4] = *(const float4*)(pa + 4);
      const float cs = cg[k0 + kr];
      const float* pb = o1g + (k0 + kr) * 256 + bj * 64 + m8;
      float4 b0 = *(const float4*)pb;
      float4 b1 = *(const float4*)(pb + 4);
      b0.x *= cs; b0.y *= cs; b0.z *= cs; b0.w *= cs;
      b1.x *= cs; b1.y *= cs; b1.z *= cs; b1.w *= cs;
      *(float4*)&Bt[kr][m8]     = b0;
      *(float4*)&Bt[kr][m8 + 4] = b1;
    }
    __syncthreads();
#pragma unroll
    for (int kk = 0; kk < 32; kk++) {
      const float4 a = *(const float4*)&At[kk][ty * 4];
      const float4 b = *(const float4*)&Bt[kk][tx * 4];
      FMA16(c, a, b)
    }
  }
  const float s1f = sclg[0];
#pragma unroll
  for (int ii = 0; ii < 4; ii++) {
    const int row = bi * 64 + ty * 4 + ii;
    const float4 w = *(const float4*)(W1g + row * 256 + bj * 64 + tx * 4);
    *(float4*)(outW1 + row * 256 + bj * 64 + tx * 4) =
        make_float4(s1f * (w.x + c[ii][0]), s1f * (w.y + c[ii][1]),
                    s1f * (w.z + c[ii][2]), s1f * (w.w + c[ii][3]));
  }
}

// ---------------------------------------------------------------- k2_seq ----
__device__ __forceinline__ float block_reduce8(float v, float* tmp, int tid) {
#pragma unroll
  for (int off = 32; off > 0; off >>= 1) v += __shfl_xor(v, off);
  __syncthreads();
  if ((tid & 63) == 0) tmp[tid >> 6] = v;
  __syncthreads();
  float s = 0.f;
#pragma unroll
  for (int w = 0; w < 8; w++) s += tmp[w];
  __syncthreads();
  return s;
}

// (j, k, idx = j*4+k): W2_idx = W2[4*lane+j][32*w + 8*k .. +7]
#define JK_LIST(OP) OP(0,0,0) OP(0,1,1) OP(0,2,2) OP(0,3,3)                   \
                    OP(1,0,4) OP(1,1,5) OP(1,2,6) OP(1,3,7)                   \
                    OP(2,0,8) OP(2,1,9) OP(2,2,10) OP(2,3,11)                 \
                    OP(3,0,12) OP(3,1,13) OP(3,2,14) OP(3,3,15)
#define K_LIST(OP) OP(0) OP(1) OP(2) OP(3)

__global__ __launch_bounds__(512, 1) void k2_seq(
    const float* __restrict__ Tg, const float* __restrict__ W1g,
    const float* __restrict__ b1g, const float* __restrict__ W2g,
    const float* __restrict__ b2g, const float* __restrict__ W3g,
    const float* __restrict__ b3g, const float* __restrict__ G,
    const float* __restrict__ Z10, float* __restrict__ o1g,
    float* __restrict__ cg, float* __restrict__ sclg,
    float* __restrict__ outW2, float* __restrict__ outW3) {
  extern __shared__ float sm[];
  float* const zo    = sm;            // [64][272]: z1p row l until step l, then o1
  float* const Gb    = sm + 17408;    // [64][64] plain / [64][33] prefix staging
  float* const scr   = sm + 21504;    // 8448: prefix o1 staging / [8][256] o1 partials
  float* const Tb    = sm + 29952;    // [64][64] targets for this block
  float* const a1v   = sm + 34048;    // [2][256] double-buffered by step parity
  float* const zk    = sm + 34560;    // 256: z1u*a1*(1-a1) (dts0 separability)
  float* const a2v   = sm + 34816;    // 256
  float* const o2v   = sm + 35072;    // 256
  float* const b1ps  = sm + 35328;    // 256 (pre-norm physical b1)
  float* const b2ps  = sm + 35584;    // 256
  float* const zp    = sm + 35840;    // [8][64] z3 wave-partials
  float* const d3v   = sm + 36352;    // 64
  float* const b3ps  = sm + 36416;    // [2][64] parity-buffered pre-norm b3
  float* const ch    = sm + 36544;    // 64  in-block c coefficients
  float* const dpart = sm + 36608;    // 48  dot wave-partials (6 dots x 8)
  float* const sca   = sm + 36656;    // 8   {s1, rb1, s2, rb2, s3, rb3, cw2, cw3}
  float* const cpre  = sm + 36664;    // 32

  const int tid = threadIdx.x;
  const int lane = tid & 63;
  const int w = tid >> 6;             // wave 0..7
  const int p = tid >> 5, q = tid & 31;  // prefix/flush index helpers
  const int rbase = 4 * lane;         // W2 row base (0..252)
  const int cbase = 32 * w;           // W2 col base / W3 row base / o2 chunk

  // ---- persistent per-thread state as named SSA values (no arrays!) ----
  // W2_phys = s2 * R2 ; W3_phys = s3 * R3  (lazy scales)
  f32x8 W2_0, W2_1, W2_2, W2_3, W2_4, W2_5, W2_6, W2_7,
        W2_8, W2_9, W2_10, W2_11, W2_12, W2_13, W2_14, W2_15;
  f32x8 W3v8_0, W3v8_1, W3v8_2, W3v8_3;   // W3[cbase+8k+e][lane]

#define INIT_W2(j, k, idx)                                                    \
  W2_##idx = *(const f32x8*)(W2g + (rbase + j) * 256 + cbase + 8 * k);
  JK_LIST(INIT_W2)

#define INIT_W3(k)                                                            \
  { const float* p3 = W3g + (cbase + 8 * k) * 64 + lane;                      \
    W3v8_##k[0] = p3[0];   W3v8_##k[1] = p3[64];  W3v8_##k[2] = p3[128];      \
    W3v8_##k[3] = p3[192]; W3v8_##k[4] = p3[256]; W3v8_##k[5] = p3[320];      \
    W3v8_##k[6] = p3[384]; W3v8_##k[7] = p3[448]; }
  K_LIST(INIT_W3)

  if (tid < 256) { b1ps[tid] = b1g[tid]; b2ps[tid] = b2g[tid]; }
  if (tid < 64) b3ps[tid] = b3g[tid];
  if (tid == 0) {
    sca[0] = 1.f; sca[1] = 1.f; sca[2] = 1.f; sca[3] = 1.f;
    sca[4] = 1.f; sca[5] = 1.f; sca[6] = 0.f; sca[7] = 0.f;
  }

  // Initial squared norms.
  float acc1 = 0.f;
  for (int i = tid; i < 65536; i += 512) {
    const float4 v = ((const float4*)W1g)[i];
    acc1 += v.x * v.x + v.y * v.y + v.z * v.z + v.w * v.w;
  }
  const float n1init = block_reduce8(acc1, scr, tid);
  float acc2 = 0.f;
#define N2R(j, k, idx) { f32x8 tq = W2_##idx * W2_##idx; acc2 += hsum8(tq); }
  JK_LIST(N2R)
  const float n2init = block_reduce8(acc2, scr, tid);
  float acc3 = 0.f;
#define N3R(k) { f32x8 tq = W3v8_##k * W3v8_##k; acc3 += hsum8(tq); }
  K_LIST(N3R)
  const float n3init = block_reduce8(acc3, scr, tid);

  // Scalar recurrence state (meaningful on wave 0 only).
  float s1 = 1.f, s2 = 1.f, s3 = 1.f;
  double n1d = (double)n1init;
  float n2 = n2init, n3 = n3init;
  __syncthreads();

  for (int b = 0; b < 16; b++) {
    const int bs = b * 64;
    // ---- prefix: zo[row][j] = Z10[bs+row][j] + sum_{s<bs} cg[s]G[bs+row][s]o1[s][j]
    {
      f32x8 pacc0 = {0.f, 0.f, 0.f, 0.f, 0.f, 0.f, 0.f, 0.f};
      f32x8 pacc1 = pacc0, pacc2 = pacc0, pacc3 = pacc0;
      for (int c0 = 0; c0 < bs; c0 += 32) {
        __syncthreads();
        if (tid < 32) cpre[tid] = cg[c0 + tid];
        {
          const int row = tid >> 3, k4 = (tid & 7) * 4;
          const float4 gv = *(const float4*)(G + (bs + row) * 1024 + c0 + k4);
          Gb[row * 33 + k4 + 0] = gv.x; Gb[row * 33 + k4 + 1] = gv.y;
          Gb[row * 33 + k4 + 2] = gv.z; Gb[row * 33 + k4 + 3] = gv.w;
        }
#pragma unroll
        for (int u = 0; u < 4; u++) {
          const int fi = tid + u * 512;
          ((float4*)scr)[fi] = ((const float4*)(o1g + c0 * 256))[fi];
        }
        __syncthreads();
#pragma unroll 2
        for (int ss = 0; ss < 32; ss++) {
          const float cs = cpre[ss];
          const f32x8 o8 = *(const f32x8*)(scr + ss * 256 + q * 8);
          pacc0 += (Gb[(p * 4 + 0) * 33 + ss] * cs) * o8;
          pacc1 += (Gb[(p * 4 + 1) * 33 + ss] * cs) * o8;
          pacc2 += (Gb[(p * 4 + 2) * 33 + ss] * cs) * o8;
          pacc3 += (Gb[(p * 4 + 3) * 33 + ss] * cs) * o8;
        }
      }
      __syncthreads();
#define ZSTORE(rr)                                                            \
      { const int row = p * 4 + rr;                                           \
        *(f32x8*)(zo + row * 272 + q * 8) =                                   \
            *(const f32x8*)(Z10 + (bs + row) * 256 + q * 8) + pacc##rr; }
      ZSTORE(0) ZSTORE(1) ZSTORE(2) ZSTORE(3)
      // this block's 64x64 Gram square (plain layout) + targets
#pragma unroll
      for (int u = 0; u < 2; u++) {
        const int fi = tid + u * 512;
        const int row = fi >> 4, c4 = fi & 15;
        *(float4*)(Gb + row * 64 + c4 * 4) =
            *(const float4*)(G + (bs + row) * 1024 + bs + c4 * 4);
      }
      ((float4*)Tb)[tid]       = ((const float4*)(Tg + bs * 64))[tid];
      ((float4*)Tb)[tid + 512] = ((const float4*)(Tg + bs * 64))[tid + 512];
      __syncthreads();
    }

    // ---- 64 sequential steps, 4 barrier-fenced phases each
    for (int l = 0; l < 64; l++) {
      const int t = bs + l;
      const int cur = (t & 1) * 256, prv = 256 - cur;
      const int pb = (t & 1) * 64;   // b3ps parity: read pb, write 64-pb
      const float s1c = sca[0], rb1c = sca[1], s2c = sca[2],
                  rb2c = sca[3], s3c = sca[4], rb3c = sca[5];

      // ================= Phase A: deferred update + z1 history + a1 =======
      if (t > 0) {
        const float cw2 = sca[6], cw3 = sca[7];
        const f32x8 oc0 = cw2 * (*(const f32x8*)&o2v[cbase]);
        const f32x8 oc1 = cw2 * (*(const f32x8*)&o2v[cbase + 8]);
        const f32x8 oc2 = cw2 * (*(const f32x8*)&o2v[cbase + 16]);
        const f32x8 oc3 = cw2 * (*(const f32x8*)&o2v[cbase + 24]);
        const float4 a1o = *(const float4*)&a1v[prv + rbase];
        W2_0  += a1o.x * oc0; W2_1  += a1o.x * oc1;
        W2_2  += a1o.x * oc2; W2_3  += a1o.x * oc3;
        W2_4  += a1o.y * oc0; W2_5  += a1o.y * oc1;
        W2_6  += a1o.y * oc2; W2_7  += a1o.y * oc3;
        W2_8  += a1o.z * oc0; W2_9  += a1o.z * oc1;
        W2_10 += a1o.z * oc2; W2_11 += a1o.z * oc3;
        W2_12 += a1o.w * oc0; W2_13 += a1o.w * oc1;
        W2_14 += a1o.w * oc2; W2_15 += a1o.w * oc3;
        const float d3s = cw3 * d3v[lane];
        W3v8_0 += d3s * (*(const f32x8*)&a2v[cbase]);
        W3v8_1 += d3s * (*(const f32x8*)&a2v[cbase + 8]);
        W3v8_2 += d3s * (*(const f32x8*)&a2v[cbase + 16]);
        W3v8_3 += d3s * (*(const f32x8*)&a2v[cbase + 24]);
      }
      {
        const int j = tid >> 1, half = tid & 1;
        float a = 0.f;
        for (int lp = half; lp < l; lp += 2)
          a += ch[lp] * Gb[l * 64 + lp] * zo[lp * 272 + j];
        a += __shfl_xor(a, 1);
        float a1x = 0.f;
        if (half == 0) {
          const float z1u = zo[l * 272 + j] + a;
          const float z = s1c * z1u + rb1c * b1ps[j];
          a1x = 1.f / (1.f + expf(-z));
          a1v[cur + j] = a1x;
          zk[j] = z1u * a1x * (1.f - a1x);
        }
        const float v3 = wave_allred(a1x * a1x);
        if (lane == 0) dpart[w] = v3;
      }
      __syncthreads();

      // ================= Phase BC: z2 (in-wave tree) -> a2 -> z3 partials =
      float z2p, a2own;
      {
        const float4 a1q = *(const float4*)&a1v[cur + rbase];
        const f32x8 vz0 = a1q.x * W2_0 + a1q.y * W2_4 + a1q.z * W2_8  + a1q.w * W2_12;
        const f32x8 vz1 = a1q.x * W2_1 + a1q.y * W2_5 + a1q.z * W2_9  + a1q.w * W2_13;
        const f32x8 vz2 = a1q.x * W2_2 + a1q.y * W2_6 + a1q.z * W2_10 + a1q.w * W2_14;
        const f32x8 vz3 = a1q.x * W2_3 + a1q.y * W2_7 + a1q.z * W2_11 + a1q.w * W2_15;
        alignas(32) float v[32];
        *(f32x8*)&v[0] = vz0;  *(f32x8*)&v[8] = vz1;
        *(f32x8*)&v[16] = vz2; *(f32x8*)&v[24] = vz3;
        const float z2sum = xtree32(v, lane);      // total for col cbase+(lane&31)
        const int c = cbase + (lane & 31);
        z2p = s2c * z2sum;
        a2own = 1.f / (1.f + expf(-(z2p + rb2c * b2ps[c])));
        if (lane < 32) a2v[c] = a2own;
        wave_fence();
        const f32x8 a2b0 = *(const f32x8*)&a2v[cbase];
        const f32x8 a2b1 = *(const f32x8*)&a2v[cbase + 8];
        const f32x8 a2b2 = *(const f32x8*)&a2v[cbase + 16];
        const f32x8 a2b3 = *(const f32x8*)&a2v[cbase + 24];
        const f32x8 zacc = a2b0 * W3v8_0 + a2b1 * W3v8_1 +
                           a2b2 * W3v8_2 + a2b3 * W3v8_3;
        zp[w * 64 + lane] = hsum8(zacc);           // z3 partial for col j=lane
        const float v6 = wave_allred(a2own * a2own);
        if (lane == 0) dpart[8 + w] = v6;
      }
      __syncthreads();

      // ====== Phase DEF: softmax/d3 (per-wave), o2 (in-wave tree), o1 =====
      float dts5 = 0.f, dts7 = 0.f, dts10 = 0.f;   // wave 0 carries to GH
      {
        float z3s = 0.f;
#pragma unroll
        for (int w2 = 0; w2 < 8; w2++) z3s += zp[w2 * 64 + lane];
        const float z3p = s3c * z3s;
        const float a3 = 1.f / (1.f + expf(-(z3p + rb3c * b3ps[pb + lane])));
        const float e = expf(-a3);
        const float tot = wave_allred(e);
        const float outv = e / tot;
        const float d3 = (Tb[l * 64 + lane] - outv) * a3 * (1.f - a3);
        if (w == 0) {
          const float b3n = rb3c * b3ps[pb + lane] - LRC * d3;
          b3ps[(64 - pb) + lane] = b3n;
          d3v[lane] = d3;
          dts5 = wave_allred(z3p * d3);
          dts7 = wave_allred(d3 * d3);
          dts10 = wave_allred(b3n * b3n);
        }
        // E: o2 for rows cbase..cbase+31 (in-wave tree over 64 cols)
        alignas(32) float v[32];
        *(f32x8*)&v[0]  = W3v8_0 * d3;
        *(f32x8*)&v[8]  = W3v8_1 * d3;
        *(f32x8*)&v[16] = W3v8_2 * d3;
        *(f32x8*)&v[24] = W3v8_3 * d3;
        const float o2raw = xtree32(v, lane);
        const int r = cbase + (lane & 31);
        const float o2x = s3c * o2raw * a2own * (1.f - a2own);
        const float b2o = b2ps[r];
        const float b2n = rb2c * b2o - LRC * o2x;
        if (lane < 32) { b2ps[r] = b2n; o2v[r] = o2x; }
        wave_fence();
        // F: o1 partials for rows rbase..rbase+3 over this wave's 32 cols
        const f32x8 ob0 = *(const f32x8*)&o2v[cbase];
        const f32x8 ob1 = *(const f32x8*)&o2v[cbase + 8];
        const f32x8 ob2 = *(const f32x8*)&o2v[cbase + 16];
        const f32x8 ob3 = *(const f32x8*)&o2v[cbase + 24];
        const f32x8 fa0 = W2_0 * ob0 + W2_1 * ob1 + W2_2 * ob2 + W2_3 * ob3;
        const f32x8 fa1 = W2_4 * ob0 + W2_5 * ob1 + W2_6 * ob2 + W2_7 * ob3;
        const f32x8 fa2 = W2_8 * ob0 + W2_9 * ob1 + W2_10 * ob2 + W2_11 * ob3;
        const f32x8 fa3 = W2_12 * ob0 + W2_13 * ob1 + W2_14 * ob2 + W2_15 * ob3;
        const float f0 = hsum8(fa0), f1 = hsum8(fa1),
                    f2 = hsum8(fa2), f3 = hsum8(fa3);
        *(float4*)&scr[w * 256 + rbase] = make_float4(f0, f1, f2, f3);
        const float4 zkq = *(const float4*)&zk[rbase];
        const float v0 = wave_allred(zkq.x * f0 + zkq.y * f1 +
                                     zkq.z * f2 + zkq.w * f3);
        const float v2 = wave_allred(z2p * o2x);
        const float v4 = wave_allred(o2x * o2x);
        const float v9 = wave_allred(b2n * b2n);
        if (lane == 0) {
          dpart[16 + w] = v0; dpart[24 + w] = v2;
          dpart[32 + w] = v4; dpart[40 + w] = v9;
        }
      }
      __syncthreads();

      // ================= Phase GH: wave 0 reduces o1 + scalar recurrences =
      if (w == 0) {
        float4 s4 = make_float4(0.f, 0.f, 0.f, 0.f);
#pragma unroll
        for (int w2 = 0; w2 < 8; w2++) {
          const float4 pv = *(const float4*)&scr[w2 * 256 + rbase];
          s4.x += pv.x; s4.y += pv.y; s4.z += pv.z; s4.w += pv.w;
        }
        const float4 a1q = *(const float4*)&a1v[cur + rbase];
        const float o1a = s2c * s4.x * a1q.x * (1.f - a1q.x);
        const float o1b = s2c * s4.y * a1q.y * (1.f - a1q.y);
        const float o1c = s2c * s4.z * a1q.z * (1.f - a1q.z);
        const float o1d = s2c * s4.w * a1q.w * (1.f - a1q.w);
        *(float4*)&zo[l * 272 + rbase] = make_float4(o1a, o1b, o1c, o1d);
        const float4 b1q = *(const float4*)&b1ps[rbase];
        const float b1a = rb1c * b1q.x - LRC * o1a;
        const float b1b = rb1c * b1q.y - LRC * o1b;
        const float b1cc = rb1c * b1q.z - LRC * o1c;
        const float b1d = rb1c * b1q.w - LRC * o1d;
        *(float4*)&b1ps[rbase] = make_float4(b1a, b1b, b1cc, b1d);
        const float dts1 = wave_allred(o1a * o1a + o1b * o1b +
                                       o1c * o1c + o1d * o1d);
        const float dts8 = wave_allred(b1a * b1a + b1b * b1b +
                                       b1cc * b1cc + b1d * b1d);
        float dts3 = 0.f, dts6h = 0.f, dts0r = 0.f,
              dts2h = 0.f, dts4h = 0.f, dts9h = 0.f;
#pragma unroll
        for (int u = 0; u < 8; u++) {
          dts3  += dpart[u];      dts6h += dpart[8 + u];
          dts0r += dpart[16 + u]; dts2h += dpart[24 + u];
          dts4h += dpart[32 + u]; dts9h += dpart[40 + u];
        }
        const float dts0 = s2c * dts0r;
        const float dts2 = 0.5f * dts2h, dts4 = 0.5f * dts4h,
                    dts6 = 0.5f * dts6h, dts9 = 0.5f * dts9h;
        const float c1 = -LRC / s1;
        const double gtt = (double)Gb[l * 64 + l];
        n1d = n1d + 2.0 * (double)c1 * (double)dts0 +
              (double)c1 * (double)c1 * gtt * (double)dts1;
        const double w1n = (double)s1 * sqrt(n1d);
        s1 = (float)((double)s1 / fmax(w1n, (double)EPSV));
        const float n2p = n2 - 2.f * LRC * dts2 + LRC * LRC * dts3 * dts4;
        const float r2s = 1.f / fmaxf(sqrtf(n2p), EPSV);
        n2 = n2p * r2s * r2s;
        const float cw2n = -LRC / s2;
        s2 = s2 * r2s;
        const float n3p = n3 - 2.f * LRC * dts5 + LRC * LRC * dts6 * dts7;
        const float r3s = 1.f / fmaxf(sqrtf(n3p), EPSV);
        n3 = n3p * r3s * r3s;
        const float cw3n = -LRC / s3;
        s3 = s3 * r3s;
        if (lane == 0) {
          ch[l] = c1;
          sca[0] = s1;
          sca[1] = 1.f / fmaxf(sqrtf(dts8), EPSV);
          sca[2] = s2;
          sca[3] = 1.f / fmaxf(sqrtf(dts9), EPSV);
          sca[4] = s3;
          sca[5] = 1.f / fmaxf(sqrtf(dts10), EPSV);
          sca[6] = cw2n;
          sca[7] = cw3n;
        }
      }
      __syncthreads();
    }

    // ---- per-block flush of o1 (from zo) and c (from ch) to global
    {
#pragma unroll
      for (int u = 0; u < 4; u++) {
        const int chunk = tid + u * 512;          // 0..2047
        const int row = chunk >> 5, c8 = chunk & 31;
        *(f32x8*)(o1g + (bs + row) * 256 + c8 * 8) =
            *(const f32x8*)(zo + row * 272 + c8 * 8);
      }
      if (tid < 64) cg[bs + tid] = ch[tid];
    }
    // next block's prefix __syncthreads() drains these stores before reads
  }

  // ---- epilogue: apply deferred update of step 1023, write scaled outputs
  {
    const float cw2 = sca[6], cw3 = sca[7];
    const float s2f = sca[2], s3f = sca[4];
    const f32x8 oc0 = cw2 * (*(const f32x8*)&o2v[cbase]);
    const f32x8 oc1 = cw2 * (*(const f32x8*)&o2v[cbase + 8]);
    const f32x8 oc2 = cw2 * (*(const f32x8*)&o2v[cbase + 16]);
    const f32x8 oc3 = cw2 * (*(const f32x8*)&o2v[cbase + 24]);
    const float4 a1o = *(const float4*)&a1v[256 + rbase];  // parity of t=1023
    W2_0  += a1o.x * oc0; W2_1  += a1o.x * oc1;
    W2_2  += a1o.x * oc2; W2_3  += a1o.x * oc3;
    W2_4  += a1o.y * oc0; W2_5  += a1o.y * oc1;
    W2_6  += a1o.y * oc2; W2_7  += a1o.y * oc3;
    W2_8  += a1o.z * oc0; W2_9  += a1o.z * oc1;
    W2_10 += a1o.z * oc2; W2_11 += a1o.z * oc3;
    W2_12 += a1o.w * oc0; W2_13 += a1o.w * oc1;
    W2_14 += a1o.w * oc2; W2_15 += a1o.w * oc3;
    const float d3s = cw3 * d3v[lane];
    W3v8_0 += d3s * (*(const f32x8*)&a2v[cbase]);
    W3v8_1 += d3s * (*(const f32x8*)&a2v[cbase + 8]);
    W3v8_2 += d3s * (*(const f32x8*)&a2v[cbase + 16]);
    W3v8_3 += d3s * (*(const f32x8*)&a2v[cbase + 24]);

#define OUT_W2(j, k, idx)                                                     \
    *(f32x8*)(outW2 + (rbase + j) * 256 + cbase + 8 * k) = s2f * W2_##idx;
    JK_LIST(OUT_W2)
#define OUT_W3(k)                                                             \
    { float* p3 = outW3 + (cbase + 8 * k) * 64 + lane;                        \
      p3[0]   = s3f * W3v8_##k[0]; p3[64]  = s3f * W3v8_##k[1];               \
      p3[128] = s3f * W3v8_##k[2]; p3[192] = s3f * W3v8_##k[3];               \
      p3[256] = s3f * W3v8_##k[4]; p3[320] = s3f * W3v8_##k[5];               \
      p3[384] = s3f * W3v8_##k[6]; p3[448] = s3f * W3v8_##k[7]; }
    K_LIST(OUT_W3)
    if (tid == 0) sclg[0] = sca[0];
  }
}

// ---------------------------------------------------------------- launch ----
extern "C" void kernel_launch(void* const* d_in, const int* in_sizes, int n_in,
                              void* d_out, int out_size, void* d_ws,
                              size_t ws_size, hipStream_t stream) {
  (void)in_sizes; (void)n_in; (void)out_size; (void)ws_size;
  const float* X   = (const float*)d_in[0];
  const float* Tg  = (const float*)d_in[1];
  const float* W1g = (const float*)d_in[2];
  const float* b1g = (const float*)d_in[3];
  const float* W2g = (const float*)d_in[4];
  const float* b2g = (const float*)d_in[5];
  const float* W3g = (const float*)d_in[6];
  const float* b3g = (const float*)d_in[7];
  float* out = (float*)d_out;
  float* ws  = (float*)d_ws;

  float* G    = ws;
  float* Z10  = G + 1048576;
  float* o1g  = Z10 + 262144;
  float* cg   = o1g + 262144;
  float* sclg = cg + 1024;

  (void)hipFuncSetAttribute((const void*)k2_seq,
                            hipFuncAttributeMaxDynamicSharedMemorySize,
                            SMEM_BYTES);

  k_gram<<<dim3(16, 16), 256, 0, stream>>>(X, G);
  k_z10<<<dim3(4, 16), 256, 0, stream>>>(X, W1g, Z10);
  k2_seq<<<dim3(1), dim3(512), SMEM_BYTES, stream>>>(
      Tg, W1g, b1g, W2g, b2g, W3g, b3g, G, Z10, o1g, cg, sclg,
      out + 262144, out + 327680);
  k_w1out<<<dim3(4, 16), 256, 0, stream>>>(X, o1g, cg, W1g, sclg, out);
}

// Round 3
// 8963.235 us; speedup vs baseline: 1.2188x; 1.2188x over previous
//
#include <hip/hip_runtime.h>
#include <math.h>

// Backprop_29188597744223 — 1024-step sequential MLP training scan.
//
//   k_gram : G = X·Xᵀ (lower triangle + diag tiles), grid-parallel
//   k_z10  : Z10 = X·W1_init, grid-parallel
//   k2_seq : ONE workgroup, 512 threads (8 waves). R1's 10-phase structure
//            with three latency cuts:
//              * all wave reductions via DPP (row_shr/row_bcast v_add, VALU
//                rate, ~30cy) instead of __shfl_xor chains (DS pipe, ~500cy)
//              * phase A history loop split 4-way (float2 + quad-perm DPP)
//              * n2/n3/s2/s3 scalar recurrences moved onto wave 7 inside the
//                F1 phase (hidden under F1 issue); wave 0's H phase keeps
//                only the f64 n1 chain + rb1 + ch
//            W2: thread (p,q) owns rows 16p..+15 × cols 8q..+7 (16 f32x8).
//            W3: same thread owns rows 16p..+15 × cols 2q..+1 (32 scalars).
//            Lazy scales s2/s3; biases pre-norm with rb folded at use; no
//            global stores in the step loop (o1/c flushed per 64-step block).
//   k_w1out: W1_final = s1_f·(W1_init + Xᵀ·diag(c)·O1), grid-parallel

#define LRC  0.01f
#define EPSV 1e-8f

typedef float f32x8 __attribute__((ext_vector_type(8)));

#define SMEM_FLOATS 36384
#define SMEM_BYTES  (SMEM_FLOATS * 4)

#define ROWS16(OP)                                                            \
  OP(0) OP(1) OP(2) OP(3) OP(4) OP(5) OP(6) OP(7)                             \
  OP(8) OP(9) OP(10) OP(11) OP(12) OP(13) OP(14) OP(15)

__device__ __forceinline__ float hsum8(f32x8 v) {
  return ((v.s0 + v.s1) + (v.s2 + v.s3)) + ((v.s4 + v.s5) + (v.s6 + v.s7));
}

// ---- DPP reductions (VALU-rate; no DS pipe) --------------------------------
template <int CTRL>
__device__ __forceinline__ float dpp_add(float v) {
  const int s = __builtin_amdgcn_update_dpp(0, __builtin_bit_cast(int, v),
                                            CTRL, 0xf, 0xf, true);
  return v + __builtin_bit_cast(float, s);
}

// Full 64-lane sum, result broadcast to all lanes via readlane(63).
__device__ __forceinline__ float dpp_allred64(float v) {
  v = dpp_add<0x111>(v);   // row_shr:1
  v = dpp_add<0x112>(v);   // row_shr:2
  v = dpp_add<0x114>(v);   // row_shr:4
  v = dpp_add<0x118>(v);   // row_shr:8  -> lane15/31/47/63 hold row sums
  v = dpp_add<0x142>(v);   // row_bcast:15
  v = dpp_add<0x143>(v);   // row_bcast:31 -> lane 63 holds total
  return __builtin_bit_cast(float,
      __builtin_amdgcn_readlane(__builtin_bit_cast(int, v), 63));
}

__device__ __forceinline__ float wave_allred(float v) {  // init-path only
#pragma unroll
  for (int off = 32; off > 0; off >>= 1) v += __shfl_xor(v, off);
  return v;
}

#define FMA16(c, a, b)                                                        \
  c[0][0] += a.x * b.x; c[0][1] += a.x * b.y; c[0][2] += a.x * b.z; c[0][3] += a.x * b.w; \
  c[1][0] += a.y * b.x; c[1][1] += a.y * b.y; c[1][2] += a.y * b.z; c[1][3] += a.y * b.w; \
  c[2][0] += a.z * b.x; c[2][1] += a.z * b.y; c[2][2] += a.z * b.z; c[2][3] += a.z * b.w; \
  c[3][0] += a.w * b.x; c[3][1] += a.w * b.y; c[3][2] += a.w * b.z; c[3][3] += a.w * b.w;

// ---------------------------------------------------------------- k_gram ----
__global__ __launch_bounds__(256) void k_gram(const float* __restrict__ X,
                                              float* __restrict__ G) {
  const int bi = blockIdx.y, bj = blockIdx.x;
  if (bj > bi) return;
  __shared__ float Xa[32][68];
  __shared__ float Xb[32][68];
  const int tid = threadIdx.x;
  const int tx = tid & 15, ty = tid >> 4;
  float c[4][4] = {};
  for (int k0 = 0; k0 < 1024; k0 += 32) {
    __syncthreads();
    {
      const int row = tid >> 2, kk = (tid & 3) * 8;
      const float* pa = X + (bi * 64 + row) * 1024 + k0 + kk;
      const float4 a0 = *(const float4*)pa;
      const float4 a1 = *(const float4*)(pa + 4);
      Xa[kk + 0][row] = a0.x; Xa[kk + 1][row] = a0.y;
      Xa[kk + 2][row] = a0.z; Xa[kk + 3][row] = a0.w;
      Xa[kk + 4][row] = a1.x; Xa[kk + 5][row] = a1.y;
      Xa[kk + 6][row] = a1.z; Xa[kk + 7][row] = a1.w;
      const float* pb = X + (bj * 64 + row) * 1024 + k0 + kk;
      const float4 b0 = *(const float4*)pb;
      const float4 b1 = *(const float4*)(pb + 4);
      Xb[kk + 0][row] = b0.x; Xb[kk + 1][row] = b0.y;
      Xb[kk + 2][row] = b0.z; Xb[kk + 3][row] = b0.w;
      Xb[kk + 4][row] = b1.x; Xb[kk + 5][row] = b1.y;
      Xb[kk + 6][row] = b1.z; Xb[kk + 7][row] = b1.w;
    }
    __syncthreads();
#pragma unroll
    for (int kk = 0; kk < 32; kk++) {
      const float4 a = *(const float4*)&Xa[kk][ty * 4];
      const float4 b = *(const float4*)&Xb[kk][tx * 4];
      FMA16(c, a, b)
    }
  }
#pragma unroll
  for (int ii = 0; ii < 4; ii++) {
    *(float4*)(G + (bi * 64 + ty * 4 + ii) * 1024 + bj * 64 + tx * 4) =
        make_float4(c[ii][0], c[ii][1], c[ii][2], c[ii][3]);
  }
}

// ----------------------------------------------------------------- k_z10 ----
__global__ __launch_bounds__(256) void k_z10(const float* __restrict__ X,
                                             const float* __restrict__ W1g,
                                             float* __restrict__ Z10) {
  const int bi = blockIdx.y, bj = blockIdx.x;
  __shared__ float At[32][68];
  __shared__ float Bt[32][68];
  const int tid = threadIdx.x;
  const int tx = tid & 15, ty = tid >> 4;
  float c[4][4] = {};
  for (int k0 = 0; k0 < 1024; k0 += 32) {
    __syncthreads();
    {
      const int row = tid >> 2, kk = (tid & 3) * 8;
      const float* pa = X + (bi * 64 + row) * 1024 + k0 + kk;
      const float4 a0 = *(const float4*)pa;
      const float4 a1 = *(const float4*)(pa + 4);
      At[kk + 0][row] = a0.x; At[kk + 1][row] = a0.y;
      At[kk + 2][row] = a0.z; At[kk + 3][row] = a0.w;
      At[kk + 4][row] = a1.x; At[kk + 5][row] = a1.y;
      At[kk + 6][row] = a1.z; At[kk + 7][row] = a1.w;
      const int kr = tid >> 3, j8 = (tid & 7) * 8;
      const float* pb = W1g + (k0 + kr) * 256 + bj * 64 + j8;
      *(float4*)&Bt[kr][j8]     = *(const float4*)pb;
      *(float4*)&Bt[kr][j8 + 4] = *(const float4*)(pb + 4);
    }
    __syncthreads();
#pragma unroll
    for (int kk = 0; kk < 32; kk++) {
      const float4 a = *(const float4*)&At[kk][ty * 4];
      const float4 b = *(const float4*)&Bt[kk][tx * 4];
      FMA16(c, a, b)
    }
  }
#pragma unroll
  for (int ii = 0; ii < 4; ii++) {
    *(float4*)(Z10 + (bi * 64 + ty * 4 + ii) * 256 + bj * 64 + tx * 4) =
        make_float4(c[ii][0], c[ii][1], c[ii][2], c[ii][3]);
  }
}

// --------------------------------------------------------------- k_w1out ----
__global__ __launch_bounds__(256) void k_w1out(
    const float* __restrict__ X, const float* __restrict__ o1g,
    const float* __restrict__ cg, const float* __restrict__ W1g,
    const float* __restrict__ sclg, float* __restrict__ outW1) {
  const int bi = blockIdx.y, bj = blockIdx.x;
  __shared__ float At[32][68];
  __shared__ float Bt[32][68];
  const int tid = threadIdx.x;
  const int tx = tid & 15, ty = tid >> 4;
  float c[4][4] = {};
  for (int k0 = 0; k0 < 1024; k0 += 32) {
    __syncthreads();
    {
      const int kr = tid >> 3, m8 = (tid & 7) * 8;
      const float* pa = X + (k0 + kr) * 1024 + bi * 64 + m8;
      *(float4*)&At[kr][m8]     = *(const float4*)pa;
      *(float4*)&At[kr][m8 + 4] = *(const float4*)(pa + 4);
      const float cs = cg[k0 + kr];
      const float* pb = o1g + (k0 + kr) * 256 + bj * 64 + m8;
      float4 b0 = *(const float4*)pb;
      float4 b1 = *(const float4*)(pb + 4);
      b0.x *= cs; b0.y *= cs; b0.z *= cs; b0.w *= cs;
      b1.x *= cs; b1.y *= cs; b1.z *= cs; b1.w *= cs;
      *(float4*)&Bt[kr][m8]     = b0;
      *(float4*)&Bt[kr][m8 + 4] = b1;
    }
    __syncthreads();
#pragma unroll
    for (int kk = 0; kk < 32; kk++) {
      const float4 a = *(const float4*)&At[kk][ty * 4];
      const float4 b = *(const float4*)&Bt[kk][tx * 4];
      FMA16(c, a, b)
    }
  }
  const float s1f = sclg[0];
#pragma unroll
  for (int ii = 0; ii < 4; ii++) {
    const int row = bi * 64 + ty * 4 + ii;
    const float4 w = *(const float4*)(W1g + row * 256 + bj * 64 + tx * 4);
    *(float4*)(outW1 + row * 256 + bj * 64 + tx * 4) =
        make_float4(s1f * (w.x + c[ii][0]), s1f * (w.y + c[ii][1]),
                    s1f * (w.z + c[ii][2]), s1f * (w.w + c[ii][3]));
  }
}

// ---------------------------------------------------------------- k2_seq ----
__device__ __forceinline__ float block_reduce8(float v, float* tmp, int tid) {
  v = wave_allred(v);
  __syncthreads();
  if ((tid & 63) == 0) tmp[tid >> 6] = v;
  __syncthreads();
  float s = 0.f;
#pragma unroll
  for (int w = 0; w < 8; w++) s += tmp[w];
  __syncthreads();
  return s;
}

__global__ __launch_bounds__(512, 1) void k2_seq(
    const float* __restrict__ Tg, const float* __restrict__ W1g,
    const float* __restrict__ b1g, const float* __restrict__ W2g,
    const float* __restrict__ b2g, const float* __restrict__ W3g,
    const float* __restrict__ b3g, const float* __restrict__ G,
    const float* __restrict__ Z10, float* __restrict__ o1g,
    float* __restrict__ cg, float* __restrict__ sclg,
    float* __restrict__ outW2, float* __restrict__ outW3) {
  extern __shared__ float sm[];
  float* const zo   = sm;            // [64][272]: z1p row l until step l, then o1
  float* const Gb   = sm + 17408;    // [64][64] plain / [64][33] prefix staging
  float* const scr  = sm + 21504;    // 8448 floats: partials / o1 staging
  float* const Tb   = sm + 29952;    // [64][64] targets for this block
  float* const a1v  = sm + 34048;    // [2][256] double-buffered by step parity
  float* const z1v  = sm + 34560;    // 256 (z1u, for dts0)
  float* const z2v  = sm + 34816;    // 256 (physical z2)
  float* const a2v  = sm + 35072;    // 256
  float* const o2v  = sm + 35328;    // 256
  float* const b1ps = sm + 35584;    // 256 (pre-norm physical b1)
  float* const b2ps = sm + 35840;    // 256
  float* const d3v  = sm + 36096;    // 64
  float* const b3ps = sm + 36160;    // 64
  float* const ch   = sm + 36224;    // 64  in-block c coefficients
  float* const dpart= sm + 36288;    // 48  dot wave-partials
  float* const sca  = sm + 36336;    // 8   {s1, rb1, s2, rb2, s3, rb3, cw2, cw3}
  float* const cpre = sm + 36352;    // 32

  const int tid = threadIdx.x;
  const int lane = tid & 63;
  const int w = tid >> 6;            // wave 0..7
  const int p = tid >> 5;            // 0..15 : 16-row group
  const int q = tid & 31;            // 0..31 : 8-col group (W2) / 2-col (W3)

  // ---- persistent per-thread state as named SSA values (no arrays!) ----
  // W2_phys = s2 * R2 ; W3_phys = s3 * R3  (lazy scales)
  f32x8 W2_0, W2_1, W2_2, W2_3, W2_4, W2_5, W2_6, W2_7,
        W2_8, W2_9, W2_10, W2_11, W2_12, W2_13, W2_14, W2_15;
  float W3x_0, W3x_1, W3x_2, W3x_3, W3x_4, W3x_5, W3x_6, W3x_7,
        W3x_8, W3x_9, W3x_10, W3x_11, W3x_12, W3x_13, W3x_14, W3x_15;
  float W3y_0, W3y_1, W3y_2, W3y_3, W3y_4, W3y_5, W3y_6, W3y_7,
        W3y_8, W3y_9, W3y_10, W3y_11, W3y_12, W3y_13, W3y_14, W3y_15;

#define INIT_ROW(i)                                                           \
  { const int row = p * 16 + i;                                               \
    W2_##i  = *(const f32x8*)(W2g + row * 256 + q * 8);                       \
    W3x_##i = W3g[row * 64 + q * 2];                                          \
    W3y_##i = W3g[row * 64 + q * 2 + 1]; }
  ROWS16(INIT_ROW)

  if (tid < 256) { b1ps[tid] = b1g[tid]; b2ps[tid] = b2g[tid]; }
  if (tid < 64) b3ps[tid] = b3g[tid];
  if (tid == 0) {
    sca[0] = 1.f; sca[1] = 1.f; sca[2] = 1.f; sca[3] = 1.f;
    sca[4] = 1.f; sca[5] = 1.f; sca[6] = 0.f; sca[7] = 0.f;
  }

  // Initial squared norms (broadcast to all threads).
  float acc1 = 0.f;
  for (int i = tid; i < 65536; i += 512) {
    const float4 v = ((const float4*)W1g)[i];
    acc1 += v.x * v.x + v.y * v.y + v.z * v.z + v.w * v.w;
  }
  const float n1init = block_reduce8(acc1, scr, tid);
  float acc2 = 0.f;
#define N2_ROW(i) { f32x8 t = W2_##i * W2_##i; acc2 += hsum8(t); }
  ROWS16(N2_ROW)
  const float n2init = block_reduce8(acc2, scr, tid);
  float acc3 = 0.f;
#define N3_ROW(i) acc3 += W3x_##i * W3x_##i + W3y_##i * W3y_##i;
  ROWS16(N3_ROW)
  const float n3init = block_reduce8(acc3, scr, tid);

  // Scalar recurrence state: wave 0 owns {s1, n1d}; wave 7 owns {s2,s3,n2,n3}.
  float s1 = 1.f, s2 = 1.f, s3 = 1.f;
  double n1d = (double)n1init;
  float n2 = n2init, n3 = n3init;
  __syncthreads();

  for (int b = 0; b < 16; b++) {
    const int bs = b * 64;
    // ---- prefix: zo[row][j] = Z10[bs+row][j] + sum_{s<bs} cg[s]G[bs+row][s]o1[s][j]
    {
      f32x8 pacc0 = {0.f, 0.f, 0.f, 0.f, 0.f, 0.f, 0.f, 0.f};
      f32x8 pacc1 = pacc0, pacc2 = pacc0, pacc3 = pacc0;
      for (int c0 = 0; c0 < bs; c0 += 32) {
        __syncthreads();
        if (tid < 32) cpre[tid] = cg[c0 + tid];
        {
          const int row = tid >> 3, k4 = (tid & 7) * 4;
          const float4 gv = *(const float4*)(G + (bs + row) * 1024 + c0 + k4);
          Gb[row * 33 + k4 + 0] = gv.x; Gb[row * 33 + k4 + 1] = gv.y;
          Gb[row * 33 + k4 + 2] = gv.z; Gb[row * 33 + k4 + 3] = gv.w;
        }
#pragma unroll
        for (int u = 0; u < 4; u++) {
          const int fi = tid + u * 512;
          ((float4*)scr)[fi] = ((const float4*)(o1g + c0 * 256))[fi];
        }
        __syncthreads();
#pragma unroll 2
        for (int ss = 0; ss < 32; ss++) {
          const float cs = cpre[ss];
          const f32x8 o8 = *(const f32x8*)(scr + ss * 256 + q * 8);
          pacc0 += (Gb[(p * 4 + 0) * 33 + ss] * cs) * o8;
          pacc1 += (Gb[(p * 4 + 1) * 33 + ss] * cs) * o8;
          pacc2 += (Gb[(p * 4 + 2) * 33 + ss] * cs) * o8;
          pacc3 += (Gb[(p * 4 + 3) * 33 + ss] * cs) * o8;
        }
      }
      __syncthreads();
#define ZSTORE(rr)                                                            \
      { const int row = p * 4 + rr;                                           \
        *(f32x8*)(zo + row * 272 + q * 8) =                                   \
            *(const f32x8*)(Z10 + (bs + row) * 256 + q * 8) + pacc##rr; }
      ZSTORE(0) ZSTORE(1) ZSTORE(2) ZSTORE(3)
      // this block's 64x64 Gram square (plain layout) + targets
#pragma unroll
      for (int u = 0; u < 2; u++) {
        const int fi = tid + u * 512;
        const int row = fi >> 4, c4 = fi & 15;
        *(float4*)(Gb + row * 64 + c4 * 4) =
            *(const float4*)(G + (bs + row) * 1024 + bs + c4 * 4);
      }
      ((float4*)Tb)[tid]       = ((const float4*)(Tg + bs * 64))[tid];
      ((float4*)Tb)[tid + 512] = ((const float4*)(Tg + bs * 64))[tid + 512];
      __syncthreads();
    }

    // ---- 64 sequential steps, 10 barrier-fenced phases each
    for (int l = 0; l < 64; l++) {
      const int t = bs + l;
      const int cur = (t & 1) * 256, prv = 256 - cur;
      const float s1c = sca[0], rb1c = sca[1], s2c = sca[2],
                  rb2c = sca[3], s3c = sca[4], rb3c = sca[5];

      // ---- Phase A: deferred W2/W3 update + z1 history (4-way) + a1 + |a1|²
      if (t > 0) {
        const float cw2 = sca[6], cw3 = sca[7];
        const f32x8 o8s = cw2 * (*(const f32x8*)&o2v[q * 8]);
        const float d0s = cw3 * d3v[q * 2], d1s = cw3 * d3v[q * 2 + 1];
#define UPD_ROW(i)                                                            \
        { const float a1o = a1v[prv + p * 16 + i];                            \
          W2_##i += a1o * o8s;                                                \
          const float a2o = a2v[p * 16 + i];                                  \
          W3x_##i += a2o * d0s; W3y_##i += a2o * d1s; }
        ROWS16(UPD_ROW)
      }
      {
        const int jp = tid >> 2, quarter = tid & 3;   // j-pair {2jp, 2jp+1}
        float ax = 0.f, ay = 0.f;
        for (int lp = quarter; lp < l; lp += 4) {
          const float gcs = ch[lp] * Gb[l * 64 + lp];
          const float2 zr = *(const float2*)&zo[lp * 272 + 2 * jp];
          ax += gcs * zr.x; ay += gcs * zr.y;
        }
        // butterfly over the 4 quad lanes (quad_perm DPP: xor1, xor2)
        ax = dpp_add<0xB1>(ax); ax = dpp_add<0x4E>(ax);
        ay = dpp_add<0xB1>(ay); ay = dpp_add<0x4E>(ay);
        const float2 zop = *(const float2*)&zo[l * 272 + 2 * jp];
        const float2 b1q = *(const float2*)&b1ps[2 * jp];
        const float z1u0 = zop.x + ax, z1u1 = zop.y + ay;
        const float a1x0 = 1.f / (1.f + expf(-(s1c * z1u0 + rb1c * b1q.x)));
        const float a1x1 = 1.f / (1.f + expf(-(s1c * z1u1 + rb1c * b1q.y)));
        if (quarter == 0) {
          *(float2*)&z1v[2 * jp] = make_float2(z1u0, z1u1);
          *(float2*)&a1v[cur + 2 * jp] = make_float2(a1x0, a1x1);
        }
        const float v3 = dpp_allred64(
            quarter == 0 ? a1x0 * a1x0 + a1x1 * a1x1 : 0.f);
        if (lane == 0) dpart[36 + w] = v3;
      }
      __syncthreads();
      // ---- B1: z2 partials = a1 @ R2
      {
        f32x8 acc = {0.f, 0.f, 0.f, 0.f, 0.f, 0.f, 0.f, 0.f};
#define B1_ROW(i) acc += a1v[cur + p * 16 + i] * W2_##i;
        ROWS16(B1_ROW)
        *(f32x8*)&scr[p * 264 + q * 8] = acc;
      }
      __syncthreads();
      // ---- B2: reduce, apply s2, sigmoid with folded rb2·b2p
      if (tid < 256) {
        float s = 0.f;
#pragma unroll
        for (int pp = 0; pp < 16; pp++) s += scr[pp * 264 + tid];
        const float z2p = s2c * s;
        z2v[tid] = z2p;
        a2v[tid] = 1.f / (1.f + expf(-(z2p + rb2c * b2ps[tid])));
      }
      __syncthreads();
      // ---- C1: z3 partials = a2 @ R3
      {
        float c0a = 0.f, c1a = 0.f;
#define C1_ROW(i)                                                             \
        { const float a2x = a2v[p * 16 + i];                                  \
          c0a += a2x * W3x_##i; c1a += a2x * W3y_##i; }
        ROWS16(C1_ROW)
        scr[(q * 2 + 0) * 17 + p] = c0a;
        scr[(q * 2 + 1) * 17 + p] = c1a;
      }
      __syncthreads();
      // ---- C2: z3, a3, softmax(-a3), d3, b3'; d3 dots (DPP)
      if (tid < 64) {
        float s = 0.f;
#pragma unroll
        for (int pp = 0; pp < 16; pp++) s += scr[tid * 17 + pp];
        const float z3p = s3c * s;
        const float a3 = 1.f / (1.f + expf(-(z3p + rb3c * b3ps[tid])));
        const float e = expf(-a3);
        const float tot = dpp_allred64(e);
        const float outv = e / tot;
        const float d3 = (Tb[l * 64 + tid] - outv) * a3 * (1.f - a3);
        d3v[tid] = d3;
        const float b3n = rb3c * b3ps[tid] - LRC * d3;
        b3ps[tid] = b3n;
        const float v5 = dpp_allred64(z3p * d3);
        const float v7 = dpp_allred64(d3 * d3);
        const float v10 = dpp_allred64(b3n * b3n);
        if (tid == 0) { dpart[32] = v5; dpart[33] = v7; dpart[34] = v10; }
      }
      __syncthreads();
      // ---- E1: o2 partials = R3 @ d3
      {
        const float d0 = d3v[q * 2 + 0], d1 = d3v[q * 2 + 1];
#define E1_ROW(i) scr[(p * 16 + i) * 33 + q] = W3x_##i * d0 + W3y_##i * d1;
        ROWS16(E1_ROW)
      }
      __syncthreads();
      // ---- E2: reduce, apply s3, sigmoid-deriv, b2'; dots (DPP)
      if (tid < 256) {
        float s = 0.f;
#pragma unroll
        for (int qq = 0; qq < 32; qq++) s += scr[tid * 33 + qq];
        const float a2x = a2v[tid];
        const float o2 = s3c * s * a2x * (1.f - a2x);
        o2v[tid] = o2;
        const float b2n = rb2c * b2ps[tid] - LRC * o2;
        b2ps[tid] = b2n;
        const float v2 = dpp_allred64(z2v[tid] * o2);
        const float v4 = dpp_allred64(o2 * o2);
        const float v6 = dpp_allred64(a2x * a2x);
        const float v9 = dpp_allred64(b2n * b2n);
        if ((tid & 63) == 0) {
          dpart[16 + w] = v2; dpart[20 + w] = v4;
          dpart[24 + w] = v6; dpart[28 + w] = v9;
        }
      }
      __syncthreads();
      // ---- F1: o1 partials = R2 @ o2 ; wave 7: n2/n3 scalar recurrences
      {
        const f32x8 ov8 = *(const f32x8*)&o2v[q * 8];
#define F1_ROW(i)                                                             \
        { f32x8 tmp = W2_##i * ov8; scr[(p * 16 + i) * 33 + q] = hsum8(tmp); }
        ROWS16(F1_ROW)
      }
      if (w == 7) {
        const float dts3 = ((dpart[36] + dpart[37]) + (dpart[38] + dpart[39]))
                         + ((dpart[40] + dpart[41]) + (dpart[42] + dpart[43]));
        const float dts2 = (dpart[16] + dpart[17]) + (dpart[18] + dpart[19]);
        const float dts4 = (dpart[20] + dpart[21]) + (dpart[22] + dpart[23]);
        const float dts6 = (dpart[24] + dpart[25]) + (dpart[26] + dpart[27]);
        const float dts9 = (dpart[28] + dpart[29]) + (dpart[30] + dpart[31]);
        const float dts5 = dpart[32], dts7 = dpart[33], dts10 = dpart[34];
        const float n2p = n2 - 2.f * LRC * dts2 + LRC * LRC * dts3 * dts4;
        const float r2s = 1.f / fmaxf(sqrtf(n2p), EPSV);
        n2 = n2p * r2s * r2s;
        const float cw2n = -LRC / s2;
        s2 = s2 * r2s;
        const float n3p = n3 - 2.f * LRC * dts5 + LRC * LRC * dts6 * dts7;
        const float r3s = 1.f / fmaxf(sqrtf(n3p), EPSV);
        n3 = n3p * r3s * r3s;
        const float cw3n = -LRC / s3;
        s3 = s3 * r3s;
        if (lane == 0) {
          sca[2] = s2;
          sca[3] = 1.f / fmaxf(sqrtf(dts9), EPSV);
          sca[4] = s3;
          sca[5] = 1.f / fmaxf(sqrtf(dts10), EPSV);
          sca[6] = cw2n;
          sca[7] = cw3n;
        }
      }
      __syncthreads();
      // ---- F2: reduce, apply s2, o1 into zo (LDS only!), b1'; dots (DPP)
      if (tid < 256) {
        float s = 0.f;
#pragma unroll
        for (int qq = 0; qq < 32; qq++) s += scr[tid * 33 + qq];
        const float a1x = a1v[cur + tid];
        const float o1x = s2c * s * a1x * (1.f - a1x);
        zo[l * 272 + tid] = o1x;          // overwrite z1p row l with o1
        const float b1n = rb1c * b1ps[tid] - LRC * o1x;
        b1ps[tid] = b1n;
        const float v0 = dpp_allred64(z1v[tid] * o1x);
        const float v1 = dpp_allred64(o1x * o1x);
        const float v8 = dpp_allred64(b1n * b1n);
        if ((tid & 63) == 0) {
          dpart[0 + w] = v0; dpart[4 + w] = v1; dpart[12 + w] = v8;
        }
      }
      __syncthreads();
      // ---- H: wave 0 only — f64 n1 recurrence, s1, rb1, ch
      if (tid < 64) {
        const float dts0 = (dpart[0] + dpart[1]) + (dpart[2] + dpart[3]);
        const float dts1 = (dpart[4] + dpart[5]) + (dpart[6] + dpart[7]);
        const float dts8 = (dpart[12] + dpart[13]) + (dpart[14] + dpart[15]);
        const float c1 = -LRC / s1;
        const double gtt = (double)Gb[l * 64 + l];
        n1d = n1d + 2.0 * (double)c1 * (double)dts0 +
              (double)c1 * (double)c1 * gtt * (double)dts1;
        const double w1n = (double)s1 * sqrt(n1d);
        s1 = (float)((double)s1 / fmax(w1n, (double)EPSV));
        if (tid == 0) {
          ch[l] = c1;
          sca[0] = s1;
          sca[1] = 1.f / fmaxf(sqrtf(dts8), EPSV);
        }
      }
      __syncthreads();
    }

    // ---- per-block flush of o1 (from zo) and c (from ch) to global
    {
#pragma unroll
      for (int u = 0; u < 4; u++) {
        const int chunk = tid + u * 512;          // 0..2047
        const int row = chunk >> 5, c8 = chunk & 31;
        *(f32x8*)(o1g + (bs + row) * 256 + c8 * 8) =
            *(const f32x8*)(zo + row * 272 + c8 * 8);
      }
      if (tid < 64) cg[bs + tid] = ch[tid];
    }
    // next block's prefix __syncthreads() drains these stores before reads
  }

  // ---- epilogue: apply deferred update of step 1023, write scaled outputs
  {
    const float cw2 = sca[6], cw3 = sca[7];
    const float s2f = sca[2], s3f = sca[4];
    const f32x8 o8s = cw2 * (*(const f32x8*)&o2v[q * 8]);
    const float d0s = cw3 * d3v[q * 2], d1s = cw3 * d3v[q * 2 + 1];
#define FIN_ROW(i)                                                            \
    { const float a1o = a1v[256 + p * 16 + i]; /* parity of t=1023 */         \
      W2_##i += a1o * o8s;                                                    \
      const float a2o = a2v[p * 16 + i];                                      \
      W3x_##i += a2o * d0s; W3y_##i += a2o * d1s;                             \
      const int row = p * 16 + i;                                             \
      *(f32x8*)(outW2 + row * 256 + q * 8) = s2f * W2_##i;                    \
      outW3[row * 64 + q * 2]     = s3f * W3x_##i;                            \
      outW3[row * 64 + q * 2 + 1] = s3f * W3y_##i; }
    ROWS16(FIN_ROW)
    if (tid == 0) sclg[0] = sca[0];
  }
}

// ---------------------------------------------------------------- launch ----
extern "C" void kernel_launch(void* const* d_in, const int* in_sizes, int n_in,
                              void* d_out, int out_size, void* d_ws,
                              size_t ws_size, hipStream_t stream) {
  (void)in_sizes; (void)n_in; (void)out_size; (void)ws_size;
  const float* X   = (const float*)d_in[0];
  const float* Tg  = (const float*)d_in[1];
  const float* W1g = (const float*)d_in[2];
  const float* b1g = (const float*)d_in[3];
  const float* W2g = (const float*)d_in[4];
  const float* b2g = (const float*)d_in[5];
  const float* W3g = (const float*)d_in[6];
  const float* b3g = (const float*)d_in[7];
  float* out = (float*)d_out;
  float* ws  = (float*)d_ws;

  float* G    = ws;
  float* Z10  = G + 1048576;
  float* o1g  = Z10 + 262144;
  float* cg   = o1g + 262144;
  float* sclg = cg + 1024;

  (void)hipFuncSetAttribute((const void*)k2_seq,
                            hipFuncAttributeMaxDynamicSharedMemorySize,
                            SMEM_BYTES);

  k_gram<<<dim3(16, 16), 256, 0, stream>>>(X, G);
  k_z10<<<dim3(4, 16), 256, 0, stream>>>(X, W1g, Z10);
  k2_seq<<<dim3(1), dim3(512), SMEM_BYTES, stream>>>(
      Tg, W1g, b1g, W2g, b2g, W3g, b3g, G, Z10, o1g, cg, sclg,
      out + 262144, out + 327680);
  k_w1out<<<dim3(4, 16), 256, 0, stream>>>(X, o1g, cg, W1g, sclg, out);
}